// Round 5
// baseline (35.343 us; speedup 1.0000x reference)
//
#include <hip/hip_runtime.h>
#include <math.h>

#define BB 4
#define RR 64
#define SS 512
#define HH 768
#define EE 64
#define SEGD 128
#define NT 6
#define NC 13
#define NP 3
#define NO (NT + NC + NP)        // 22
#define REP 2560                 // 2*H + 2*SEG + H
#define RPG 8                    // relations per phase-1 block
#define NGRP (RR / RPG)          // 8
#define NEGV -1e30f
#define SCQ 16                   // S chunks (best measured)
#define ROWS (SS / SCQ)          // 32
#define NB1 (BB * NGRP * SCQ)    // 512 max-blocks
#define NTB 64                   // W-transpose blocks appended to p1 grid
#define WT_ELEMS (REP * NO)      // 56320
#define OFF_WT ((size_t)BB * RR * SCQ * HH)   // float offset of WT in ws

// ---------------- phase 1: masked max (blocks < NB1) + W transpose (blocks >= NB1) ----
__global__ __launch_bounds__(256)
void p1_maxctx(const float* __restrict__ hidden,     // [B,S,H]
               const int*   __restrict__ rel_masks,  // [B,R,S]
               const float* __restrict__ Wt,
               const float* __restrict__ Wc,
               const float* __restrict__ Wp,
               float* __restrict__ ws)
{
    const int bid = blockIdx.x;
    const int t   = threadIdx.x;

    if (bid >= NB1) {
        // transpose the three W matrices into WT[o][f], o in [0,22)
        float* WT = ws + OFF_WT;
        for (int e = (bid - NB1) * 256 + t; e < WT_ELEMS; e += NTB * 256) {
            const int o = e / REP;
            const int f = e - o * REP;
            float v;
            if (o < NT)           v = Wt[(size_t)f * NT + o];
            else if (o < NT + NC) v = Wc[(size_t)f * NC + (o - NT)];
            else                  v = Wp[(size_t)f * NP + (o - NT - NC)];
            WT[e] = v;
        }
        return;
    }

    const int sc  = bid % SCQ;
    const int grp = (bid / SCQ) % NGRP;
    const int b   = bid / (SCQ * NGRP);
    const int s0  = sc * ROWS;
    const int r0  = grp * RPG;

    __shared__ float sadd[RPG * ROWS];   // 256 floats
    {
        const int r = t / ROWS;
        const int s = t - r * ROWS;
        const int mv = rel_masks[((size_t)(b * RR + r0 + r)) * SS + s0 + s];
        sadd[t] = mv ? 0.f : NEGV;
    }
    __syncthreads();

    float m[RPG][3];
#pragma unroll
    for (int r = 0; r < RPG; ++r) { m[r][0] = -INFINITY; m[r][1] = -INFINITY; m[r][2] = -INFINITY; }

    const float* hbase = hidden + ((size_t)b * SS + s0) * HH + t;
#pragma unroll 8
    for (int s = 0; s < ROWS; ++s) {
        const float* hp = hbase + (size_t)s * HH;
        const float v0 = hp[0];
        const float v1 = hp[256];
        const float v2 = hp[512];
#pragma unroll
        for (int r = 0; r < RPG; ++r) {
            const float a = sadd[r * ROWS + s];
            m[r][0] = fmaxf(m[r][0], v0 + a);
            m[r][1] = fmaxf(m[r][1], v1 + a);
            m[r][2] = fmaxf(m[r][2], v2 + a);
        }
    }

#pragma unroll
    for (int r = 0; r < RPG; ++r) {
        float* wp = ws + (((size_t)(b * RR + r0 + r)) * SCQ + sc) * HH + t;
        wp[0]   = m[r][0];
        wp[256] = m[r][1];
        wp[512] = m[r][2];
    }
}

// ---------------- phase 2: parallel reduce+gather, coalesced WT matvec ----------------
__global__ __launch_bounds__(256)
void p2_head(const float* __restrict__ ws,          // partials + WT
             const int*   __restrict__ rel_pairs,   // [B,R,2] (int32 from harness)
             const float* __restrict__ span,        // [B,E,H]
             const float* __restrict__ segs,        // [B,E,SEG]
             const float* __restrict__ bt,
             const float* __restrict__ bc,
             const float* __restrict__ bp,
             float* __restrict__ out)
{
    const int br = blockIdx.x;
    const int b  = br / RR;
    const int t  = threadIdx.x;

    __shared__ float feat[REP];
    __shared__ float red[4][NO];

    const int i0 = rel_pairs[(size_t)br * 2 + 0];
    const int i1 = rel_pairs[(size_t)br * 2 + 1];
    const int CTX0 = 2 * HH + 2 * SEGD;   // 1792

    if (t < 192) {
        // reduce SCQ partial maxes, full unroll -> 16 independent float4 loads
        float4 mm = make_float4(-INFINITY, -INFINITY, -INFINITY, -INFINITY);
        const float* wbase = ws + (size_t)br * SCQ * HH + 4 * t;
#pragma unroll
        for (int c = 0; c < SCQ; ++c) {
            const float4 w = *reinterpret_cast<const float4*>(wbase + (size_t)c * HH);
            mm.x = fmaxf(mm.x, w.x);
            mm.y = fmaxf(mm.y, w.y);
            mm.z = fmaxf(mm.z, w.z);
            mm.w = fmaxf(mm.w, w.w);
        }
        // all-masked rows collapse to ~-1e30; reference zeroes them
        if (mm.x < -1e29f) mm.x = 0.f;
        if (mm.y < -1e29f) mm.y = 0.f;
        if (mm.z < -1e29f) mm.z = 0.f;
        if (mm.w < -1e29f) mm.w = 0.f;
        *reinterpret_cast<float4*>(&feat[CTX0 + 4 * t]) = mm;
    } else {
        // gather span/seg embeddings: 448 float4s over 64 threads
        for (int k = t - 192; k < 448; k += 64) {
            float4 v; int dst;
            if (k < 192) {
                v = *reinterpret_cast<const float4*>(span + ((size_t)b * EE + i0) * HH + 4 * k);
                dst = 4 * k;
            } else if (k < 384) {
                const int u = k - 192;
                v = *reinterpret_cast<const float4*>(span + ((size_t)b * EE + i1) * HH + 4 * u);
                dst = HH + 4 * u;
            } else if (k < 416) {
                const int u = k - 384;
                v = *reinterpret_cast<const float4*>(segs + ((size_t)b * EE + i0) * SEGD + 4 * u);
                dst = 2 * HH + 4 * u;
            } else {
                const int u = k - 416;
                v = *reinterpret_cast<const float4*>(segs + ((size_t)b * EE + i1) * SEGD + 4 * u);
                dst = 2 * HH + SEGD + 4 * u;
            }
            *reinterpret_cast<float4*>(&feat[dst]) = v;
        }
    }
    __syncthreads();

    // matvec: thread t owns f = {4t, 4t+1024, 4t+2048(<REP)} as float4, WT coalesced
    const float* WT = ws + OFF_WT;
    const float4 f0 = *reinterpret_cast<const float4*>(&feat[4 * t]);
    const float4 f1 = *reinterpret_cast<const float4*>(&feat[4 * t + 1024]);
    const bool has2 = (t < 128);          // wave-uniform (waves 0,1)
    float4 f2 = make_float4(0.f, 0.f, 0.f, 0.f);
    if (has2) f2 = *reinterpret_cast<const float4*>(&feat[4 * t + 2048]);

    float acc[NO];
#pragma unroll 4
    for (int o = 0; o < NO; ++o) {
        const float* row = WT + (size_t)o * REP + 4 * t;
        const float4 w0 = *reinterpret_cast<const float4*>(row);
        const float4 w1 = *reinterpret_cast<const float4*>(row + 1024);
        float s = f0.x * w0.x + f0.y * w0.y + f0.z * w0.z + f0.w * w0.w
                + f1.x * w1.x + f1.y * w1.y + f1.z * w1.z + f1.w * w1.w;
        if (has2) {
            const float4 w2 = *reinterpret_cast<const float4*>(row + 2048);
            s += f2.x * w2.x + f2.y * w2.y + f2.z * w2.z + f2.w * w2.w;
        }
        acc[o] = s;
    }

#pragma unroll
    for (int o = 0; o < NO; ++o) {
#pragma unroll
        for (int off = 32; off > 0; off >>= 1)
            acc[o] += __shfl_down(acc[o], off, 64);
    }
    const int wid  = t >> 6;
    const int lane = t & 63;
    if (lane == 0) {
#pragma unroll
        for (int o = 0; o < NO; ++o) red[wid][o] = acc[o];
    }
    __syncthreads();

    if (t < NO) {
        const float v = red[0][t] + red[1][t] + red[2][t] + red[3][t];
        if (t < NT) {
            out[(size_t)br * NT + t] = v + bt[t];
        } else if (t < NT + NC) {
            const int o = t - NT;
            out[(size_t)BB * RR * NT + (size_t)br * NC + o] = v + bc[o];
        } else {
            const int o = t - NT - NC;
            out[(size_t)BB * RR * (NT + NC) + (size_t)br * NP + o] = v + bp[o];
        }
    }
}

// ---------------- fallback: fused single kernel (if ws too small) ----------------
__global__ __launch_bounds__(256)
void rel_cls_fused(const float* __restrict__ hidden,
                   const int*   __restrict__ rel_pairs,
                   const int*   __restrict__ rel_masks,
                   const float* __restrict__ span,
                   const float* __restrict__ segs,
                   const float* __restrict__ Wt, const float* __restrict__ bt,
                   const float* __restrict__ Wc, const float* __restrict__ bc,
                   const float* __restrict__ Wp, const float* __restrict__ bp,
                   float* __restrict__ out)
{
    const int br = blockIdx.x;
    const int b  = br / RR;
    const int t  = threadIdx.x;

    __shared__ float sadd[SS];
    __shared__ float feat[REP];
    __shared__ float red[4][NO];

    const int* mrow = rel_masks + (size_t)br * SS;
    sadd[t]       = mrow[t] ? 0.f : NEGV;
    sadd[t + 256] = mrow[t + 256] ? 0.f : NEGV;

    const int i0 = rel_pairs[(size_t)br * 2 + 0];
    const int i1 = rel_pairs[(size_t)br * 2 + 1];
    const float* sp0 = span + ((size_t)b * EE + i0) * HH;
    const float* sp1 = span + ((size_t)b * EE + i1) * HH;
    feat[t]            = sp0[t];
    feat[t + 256]      = sp0[t + 256];
    feat[t + 512]      = sp0[t + 512];
    feat[HH + t]       = sp1[t];
    feat[HH + t + 256] = sp1[t + 256];
    feat[HH + t + 512] = sp1[t + 512];
    const float* sg0 = segs + ((size_t)b * EE + i0) * SEGD;
    const float* sg1 = segs + ((size_t)b * EE + i1) * SEGD;
    if (t < SEGD) feat[2 * HH + t] = sg0[t];
    else          feat[2 * HH + SEGD + (t - SEGD)] = sg1[t - SEGD];
    __syncthreads();

    float m0 = -INFINITY, m1 = -INFINITY, m2 = -INFINITY;
#pragma unroll 8
    for (int s = 0; s < SS; ++s) {
        const float* hp = hidden + ((size_t)b * SS + s) * HH;
        const float a = sadd[s];
        m0 = fmaxf(m0, hp[t] + a);
        m1 = fmaxf(m1, hp[t + 256] + a);
        m2 = fmaxf(m2, hp[t + 512] + a);
    }
    if (m0 < -1e29f) m0 = 0.f;
    if (m1 < -1e29f) m1 = 0.f;
    if (m2 < -1e29f) m2 = 0.f;
    const int CTX0 = 2 * HH + 2 * SEGD;
    feat[CTX0 + t]       = m0;
    feat[CTX0 + t + 256] = m1;
    feat[CTX0 + t + 512] = m2;
    __syncthreads();

    float acc[NO];
#pragma unroll
    for (int o = 0; o < NO; ++o) acc[o] = 0.f;
    for (int f = t; f < REP; f += 256) {
        const float fv = feat[f];
        const float* wt = Wt + (size_t)f * NT;
        const float* wc = Wc + (size_t)f * NC;
        const float* wp = Wp + (size_t)f * NP;
#pragma unroll
        for (int o = 0; o < NT; ++o) acc[o]           += fv * wt[o];
#pragma unroll
        for (int o = 0; o < NC; ++o) acc[NT + o]      += fv * wc[o];
#pragma unroll
        for (int o = 0; o < NP; ++o) acc[NT + NC + o] += fv * wp[o];
    }
#pragma unroll
    for (int o = 0; o < NO; ++o) {
#pragma unroll
        for (int off = 32; off > 0; off >>= 1)
            acc[o] += __shfl_down(acc[o], off, 64);
    }
    const int wid  = t >> 6;
    const int lane = t & 63;
    if (lane == 0) {
#pragma unroll
        for (int o = 0; o < NO; ++o) red[wid][o] = acc[o];
    }
    __syncthreads();

    if (t < NO) {
        const float v = red[0][t] + red[1][t] + red[2][t] + red[3][t];
        if (t < NT) {
            out[(size_t)br * NT + t] = v + bt[t];
        } else if (t < NT + NC) {
            const int o = t - NT;
            out[(size_t)BB * RR * NT + (size_t)br * NC + o] = v + bc[o];
        } else {
            const int o = t - NT - NC;
            out[(size_t)BB * RR * (NT + NC) + (size_t)br * NP + o] = v + bp[o];
        }
    }
}

extern "C" void kernel_launch(void* const* d_in, const int* in_sizes, int n_in,
                              void* d_out, int out_size, void* d_ws, size_t ws_size,
                              hipStream_t stream) {
    const float* hidden = (const float*)d_in[0];
    const int*   pairs  = (const int*)d_in[1];
    const int*   masks  = (const int*)d_in[2];
    const float* span   = (const float*)d_in[4];
    const float* segs   = (const float*)d_in[5];
    const float* Wt     = (const float*)d_in[6];
    const float* bt     = (const float*)d_in[7];
    const float* Wc     = (const float*)d_in[8];
    const float* bc     = (const float*)d_in[9];
    const float* Wp     = (const float*)d_in[10];
    const float* bp     = (const float*)d_in[11];
    float* out = (float*)d_out;
    float* ws  = (float*)d_ws;

    const size_t need = (OFF_WT + (size_t)WT_ELEMS) * sizeof(float);  // ~12.8 MB

    if (ws_size >= need) {
        dim3 g1(NB1 + NTB), blk(256);
        hipLaunchKernelGGL(p1_maxctx, g1, blk, 0, stream,
                           hidden, masks, Wt, Wc, Wp, ws);
        dim3 g2(BB * RR);
        hipLaunchKernelGGL(p2_head, g2, blk, 0, stream,
                           ws, pairs, span, segs, bt, bc, bp, out);
    } else {
        dim3 grid(BB * RR), blk(256);
        hipLaunchKernelGGL(rel_cls_fused, grid, blk, 0, stream,
                           hidden, pairs, masks, span, segs,
                           Wt, bt, Wc, bc, Wp, bp, out);
    }
}